// Round 4
// baseline (17417.252 us; speedup 1.0000x reference)
//
#include <hip/hip_runtime.h>
#include <hip/hip_bf16.h>
#include <cstdint>
#include <cstddef>

// ============================================================================
// BiSLSTM (B=32, S=1024, E=256, H=256, K=2), fp32 in/out.  Round 6.
//
// Replicated-s architecture (one exchange/step, verified R3-R5) with a
// per-line TAGGED-RECORD protocol replacing flag+ack+gather:
//   * REC: per (pc,d,g,b) two 64B lines: line0 [tag|h|c_hi|c_lo] (c as
//     bf16-pair ~= f32), line1 [tag|rsx].  Tags compared by EQUALITY to
//     want=t+1 -> 0xAA poison is never fresh, no zeroing needed.
//   * producer: store data chunks; vmcnt(0) ONLY on wave0 (waves1-3 overlap
//     with x-prefetch/zacc/rsx MFMAs); then fire 32 tag stores.  rsx lines
//     published one step EARLY (tag t+2 during step t) -> pre-fresh at poll.
//   * consumer: per-wave tag poll of its 512-line quarter (spread over 4096
//     lines vs R5's 64 flag lines -> ~64x less per-line contention), then
//     bulk gather + LDS scatter, no barrier between detect and gather.
//   * barriers/step 6 -> 4 (S1 z, S2 gates, S4 gather, S5 P4).
// ============================================================================

typedef __bf16 bf16x8 __attribute__((ext_vector_type(8)));
typedef float  f32x4  __attribute__((ext_vector_type(4)));
typedef unsigned long long u64x2 __attribute__((ext_vector_type(2)));
typedef unsigned long long u64;

#define DEVINL __device__ __forceinline__

constexpr int Ss = 1024;

// ---- ws layout (bytes) ----
constexpr size_t OFF_REC = 4096;                   // [2pc][2d][2048 lines][64B]
constexpr size_t SZ_REC  = (size_t)2*2*2048*64;    // 512 KB
constexpr size_t OFF_WH  = OFF_REC + SZ_REC;       // [2][1024 col][256 k] bf16
constexpr size_t SZ_W    = (size_t)2*1024*256*2;   // 1 MB
constexpr size_t OFF_WX  = OFF_WH + SZ_W;
constexpr size_t OFF_WS  = OFF_WX + SZ_W;
constexpr size_t OFF_WRX = OFF_WS + SZ_W;          // [2][2*256 j][256 k] bf16
constexpr size_t SZ_WR   = (size_t)2*2*256*256*2;  // 512 KB
constexpr size_t OFF_WRH = OFF_WRX + SZ_WR;        // end ~4.8 MB

DEVINL unsigned short f2bf(float f) {                 // RNE fp32->bf16
    unsigned u = __builtin_bit_cast(unsigned, f);
    u += 0x7FFFu + ((u >> 16) & 1u);
    return (unsigned short)(u >> 16);
}
DEVINL u64 pack4(float4 v) {
    return (u64)f2bf(v.x) | ((u64)f2bf(v.y) << 16)
         | ((u64)f2bf(v.z) << 32) | ((u64)f2bf(v.w) << 48);
}
DEVINL float bfhi(unsigned short h) { return __builtin_bit_cast(float, (unsigned)h << 16); }
DEVINL float sigm(float x) { return 1.f / (1.f + __expf(-x)); }

DEVINL u64 ald64(const u64* p) {
    return __hip_atomic_load(p, __ATOMIC_RELAXED, __HIP_MEMORY_SCOPE_AGENT);
}
DEVINL unsigned ald32(const unsigned* p) {
    return __hip_atomic_load(p, __ATOMIC_RELAXED, __HIP_MEMORY_SCOPE_AGENT);
}
DEVINL void ast32u(unsigned* p, unsigned v) {
    __hip_atomic_store(p, v, __ATOMIC_RELAXED, __HIP_MEMORY_SCOPE_AGENT);
}
DEVINL void gst16(void* p, u64x2 v) {               // 16B device-scope store
    asm volatile("global_store_dwordx4 %0, %1, off sc1" :: "v"(p), "v"(v) : "memory");
}

// ---------------------------------------------------------------------------
__global__ void prepass(const float* __restrict__ Wx0, const float* __restrict__ Wh0,
                        const float* __restrict__ Ws0,
                        const float* __restrict__ Wx1, const float* __restrict__ Wh1,
                        const float* __restrict__ Ws1,
                        const float* __restrict__ Wrx0, const float* __restrict__ Wrh0,
                        const float* __restrict__ Wrx1, const float* __restrict__ Wrh1,
                        unsigned char* __restrict__ ws)
{
    unsigned short* whT  = (unsigned short*)(ws + OFF_WH);
    unsigned short* wxT  = (unsigned short*)(ws + OFF_WX);
    unsigned short* wsT  = (unsigned short*)(ws + OFF_WS);
    unsigned short* wrxT = (unsigned short*)(ws + OFF_WRX);
    unsigned short* wrhT = (unsigned short*)(ws + OFF_WRH);
    int tid = blockIdx.x * blockDim.x + threadIdx.x;
    int NT  = gridDim.x * blockDim.x;
    for (int e = tid; e < 2*1024*256; e += NT) {
        int d = e >> 18, r = e & 262143, n = r >> 8, k = r & 255;
        whT[e] = f2bf((d ? Wh1 : Wh0)[k*1024 + n]);
        wxT[e] = f2bf((d ? Wx1 : Wx0)[k*1024 + n]);
        wsT[e] = f2bf((d ? Ws1 : Ws0)[k*1024 + n]);
    }
    for (int e = tid; e < 2*2*256*256; e += NT) {
        int d = e >> 17, r = e & 131071, kk = r >> 16, r2 = r & 65535;
        int j = r2 >> 8, k = r2 & 255;
        wrxT[e] = f2bf((d ? Wrx1 : Wrx0)[(kk*256 + k)*256 + j]);
        wrhT[e] = f2bf((d ? Wrh1 : Wrh0)[(kk*256 + k)*256 + j]);
    }
    // REC region needs no init: tags use EQUALITY vs want in [1,1025];
    // 0xAAAAAAAA poison never matches.
}

// ---------------------------------------------------------------------------
// sA: u16[2 Mt][16 kt][4 lq][16 m][8].  kt 0..7 = h, 8..15 = s.
__launch_bounds__(256, 1)
__global__ void bislstm(const float* __restrict__ inputs, const float* __restrict__ mask,
                        const float* __restrict__ b0,  const float* __restrict__ b1,
                        const float* __restrict__ br0, const float* __restrict__ br1,
                        const int* __restrict__ idxp,
                        unsigned char* __restrict__ ws, float* __restrict__ out)
{
    const int bid = blockIdx.x;
    const int d   = bid >> 5;
    const int g   = bid & 31;
    const int tid = threadIdx.x;
    const int wave = tid >> 6, lane = tid & 63;
    const int lm = lane & 15, lq = lane >> 4;

    __shared__ __align__(16) unsigned short sA[16384];    // 32 KB frags (h,s)
    __shared__ __align__(16) unsigned short chiL[32][264];
    __shared__ __align__(16) unsigned short cloL[32][264];
    __shared__ __align__(16) unsigned short rL[32][264];
    __shared__ __align__(16) unsigned pubA[32][16];       // line0 images (2 KB)
    __shared__ __align__(16) unsigned pubB[32][4];        // line1 chunk1 (512 B)
    __shared__ float zs[2][32][16];
    __shared__ float rsxS[2][32][16];
    __shared__ float rshS[32][16];
    __shared__ float mL[32];

    const unsigned short* whT  = (const unsigned short*)(ws + OFF_WH)  + (size_t)d*1024*256;
    const unsigned short* wxT  = (const unsigned short*)(ws + OFF_WX)  + (size_t)d*1024*256;
    const unsigned short* wsT  = (const unsigned short*)(ws + OFF_WS)  + (size_t)d*1024*256;
    const unsigned short* wrxT = (const unsigned short*)(ws + OFF_WRX) + (size_t)d*2*256*256;
    const unsigned short* wrhT = (const unsigned short*)(ws + OFF_WRH) + (size_t)d*2*256*256;
    const int idxv = idxp[0];
    const float* bd  = d ? b1  : b0;
    const float* brd = d ? br1 : br0;

    const int zMt = wave & 1, zNt = wave >> 1;
    const int znl = zNt*16 + lm;
    const int zcol = (znl >> 3)*256 + g*8 + (znl & 7);
    const int rks = lm >> 3;
    const int rj  = g*8 + (lm & 7);

    // ---- preload weight B-fragments ----
    bf16x8 whf[8], wsf[8], wxf[8], rwf[8], wbig[4][8];
#pragma unroll
    for (int kt = 0; kt < 8; ++kt) {
        whf[kt] = *(const bf16x8*)(whT + (size_t)zcol*256 + kt*32 + lq*8);
        wsf[kt] = *(const bf16x8*)(wsT + (size_t)zcol*256 + kt*32 + lq*8);
        wxf[kt] = *(const bf16x8*)(wxT + (size_t)zcol*256 + kt*32 + lq*8);
    }
    {
        const unsigned short* wrT = (wave < 2) ? wrhT : wrxT;
#pragma unroll
        for (int kt = 0; kt < 8; ++kt)
            rwf[kt] = *(const bf16x8*)(wrT + (size_t)(rks*256 + rj)*256 + kt*32 + lq*8);
    }
    float brj[16];
#pragma unroll
    for (int n = 0; n < 4; ++n) {
        const int j16 = wave*64 + n*16 + lm;
#pragma unroll
        for (int kt = 0; kt < 8; ++kt)
            wbig[n][kt] = *(const bf16x8*)(wrhT + (size_t)(idxv*256 + j16)*256 + kt*32 + lq*8);
#pragma unroll
        for (int r = 0; r < 4; ++r)
            brj[n*4 + r] = brd[idxv*256 + wave*64 + n*16 + lq*4 + r];
    }

    // ---- zero sA (h_{-1}=s_{-1}=0) ----
    {
        u64* z8 = (u64*)sA;
#pragma unroll
        for (int i = 0; i < 16; ++i) z8[tid + 256*i] = 0ULL;
    }

    // ---- prologue: x_0 -> zacc + rsx_0 (waves>=2, staged into rsxS/pubB) ----
    f32x4 zacc;
    {
        const int tx0 = d ? (Ss - 1) : 0;
        const float* xp = inputs + (((size_t)(zMt*16 + lm)*Ss + tx0) << 8) + lq*8;
        bf16x8 xf[8];
#pragma unroll
        for (int kt = 0; kt < 8; ++kt) {
            float4 v0 = *(const float4*)(xp + kt*32);
            float4 v1 = *(const float4*)(xp + kt*32 + 4);
            u64x2 pk; pk.x = pack4(v0); pk.y = pack4(v1);
            xf[kt] = __builtin_bit_cast(bf16x8, pk);
        }
        f32x4 a = {0.f, 0.f, 0.f, 0.f};
#pragma unroll
        for (int kt = 0; kt < 8; ++kt)
            a = __builtin_amdgcn_mfma_f32_16x16x32_bf16(xf[kt], wxf[kt], a, 0, 0, 0);
        zacc = a;
        if (wave >= 2) {
            f32x4 ra = {0.f, 0.f, 0.f, 0.f};
#pragma unroll
            for (int kt = 0; kt < 8; ++kt)
                ra = __builtin_amdgcn_mfma_f32_16x16x32_bf16(xf[kt], rwf[kt], ra, 0, 0, 0);
#pragma unroll
            for (int r = 0; r < 4; ++r) {
                const int b = zMt*16 + lq*4 + r;
                rsxS[0][b][lm] = ra[r];
                if (rks == idxv) ((unsigned short*)pubB[b])[lm & 7] = f2bf(ra[r]);
            }
        }
    }
    __syncthreads();
    if (wave == 3) {          // publish rsx_0 lines (parity 0, tag 1)
        if (lane < 32) {
            u64x2 v = *(const u64x2*)&pubB[lane][0];
            gst16((u64*)(ws + OFF_REC) + ((size_t)d*2048 + g*64 + lane*2 + 1)*8 + 2, v);
        }
        asm volatile("s_waitcnt vmcnt(0)" ::: "memory");
        if (lane < 32)
            ast32u((unsigned*)(ws + OFF_REC) + ((size_t)d*2048 + g*64 + lane*2 + 1)*16, 1u);
    }

    // per-thread elementwise constants + state
    const int eb = tid >> 3, ej = tid & 7;
    const int gj = g*8 + ej;
    const float bias_i = bd[gj], bias_f = bd[256+gj], bias_g = bd[512+gj], bias_o = bd[768+gj];
    const float brr0 = brd[gj], brr1 = brd[256+gj];
    float hprev = 0.f, cprev = 0.f, s1prev = 0.f;
    float sreg[2][4][4] = {};     // replicated s[idx]: j=wave*64+n*16+lq*4+r, b=Mt*16+lm

    const unsigned short* aBase = sA + (size_t)(zMt*8192 + lq*128 + lm*8);

#pragma unroll 1
    for (int t = 0; t < Ss; ++t) {
        const int tx = d ? (Ss - 1 - t) : t;
        const int pc = t & 1, pcn = pc ^ 1;
        const unsigned want = (unsigned)(t + 1);
        const bool more = (t + 1 < Ss);

        // ---- P1: z = zacc + h@Wh + s@Ws (frags from LDS) ----
        if (tid < 32) mL[tid] = mask[(size_t)tid*Ss + tx];
        {
            f32x4 acc = zacc;
#pragma unroll
            for (int kt = 0; kt < 8; ++kt)
                acc = __builtin_amdgcn_mfma_f32_16x16x32_bf16(*(const bf16x8*)(aBase + kt*512), whf[kt], acc, 0, 0, 0);
#pragma unroll
            for (int kt = 0; kt < 8; ++kt)
                acc = __builtin_amdgcn_mfma_f32_16x16x32_bf16(*(const bf16x8*)(aBase + (8+kt)*512), wsf[kt], acc, 0, 0, 0);
#pragma unroll
            for (int r = 0; r < 4; ++r)
                zs[zNt][zMt*16 + lq*4 + r][lm] = acc[r];
        }
        __syncthreads();                                   // S1

        // ---- P2: gates -> c,h ; stage line0 image (h, c_hi, c_lo) ----
        float m_, cu_, hu_;
        {
            float zi = zs[0][eb][ej]   + bias_i;
            float zf = zs[0][eb][8+ej] + bias_f;
            float zg = zs[1][eb][ej]   + bias_g;
            float zo = zs[1][eb][8+ej] + bias_o;
            float cn = sigm(zf)*cprev + sigm(zi)*tanhf(zg);
            float hn = sigm(zo)*tanhf(cn);
            m_  = mL[eb];
            cu_ = m_*cn + (1.f - m_)*cprev;
            hu_ = m_*hn + (1.f - m_)*hprev;
            cprev = cu_; hprev = hu_;
            unsigned short chi = f2bf(cu_);
            unsigned short clo = f2bf(cu_ - bfhi(chi));
            unsigned short* pa = (unsigned short*)pubA[eb];
            pa[8  + ej] = f2bf(hu_);
            pa[16 + ej] = chi;
            pa[24 + ej] = clo;
        }
        __syncthreads();                                   // S2

        // ---- P2b: wave0 publishes line0 data -> vmcnt -> tags (others go on) ----
        if (wave == 0) {
#pragma unroll
            for (int inst = 0; inst < 2; ++inst) {
                if ((lane & 3) != 0) {
                    const int b = inst*16 + (lane >> 2);
                    u64x2 v = *(const u64x2*)((const unsigned char*)pubA + inst*1024 + lane*16);
                    gst16((u64*)(ws + OFF_REC) + ((size_t)(pc*2 + d)*16384 + ((size_t)g*64 + b*2)*8) + (lane & 3)*2, v);
                }
            }
            asm volatile("s_waitcnt vmcnt(0)" ::: "memory");
            if (lane < 32)
                ast32u((unsigned*)(ws + OFF_REC) + (size_t)(pc*2 + d)*32768 + ((size_t)g*64 + lane*2)*16, want);
        }

        // ---- P3: out h/c ; x' prefetch + zacc' + rsx' (overlaps publish/poll) ----
        out[((size_t)tx*32 + eb)*512 + d*256 + gj] = hu_;
        out[16777216 + ((size_t)tx*32 + eb)*512 + d*256 + gj] = cu_;
        if (more) {
            const int txn = d ? (Ss - 2 - t) : (t + 1);
            const float* xp = inputs + (((size_t)(zMt*16 + lm)*Ss + txn) << 8) + lq*8;
            bf16x8 xf[8];
#pragma unroll
            for (int kt = 0; kt < 8; ++kt) {
                float4 v0 = *(const float4*)(xp + kt*32);
                float4 v1 = *(const float4*)(xp + kt*32 + 4);
                u64x2 pk; pk.x = pack4(v0); pk.y = pack4(v1);
                xf[kt] = __builtin_bit_cast(bf16x8, pk);
            }
            f32x4 a = {0.f, 0.f, 0.f, 0.f};
#pragma unroll
            for (int kt = 0; kt < 8; ++kt)
                a = __builtin_amdgcn_mfma_f32_16x16x32_bf16(xf[kt], wxf[kt], a, 0, 0, 0);
            zacc = a;
            if (wave >= 2) {       // rsx_{t+1}: own 16 cols, both shares; stage pubB (idx share)
                f32x4 ra = {0.f, 0.f, 0.f, 0.f};
#pragma unroll
                for (int kt = 0; kt < 8; ++kt)
                    ra = __builtin_amdgcn_mfma_f32_16x16x32_bf16(xf[kt], rwf[kt], ra, 0, 0, 0);
#pragma unroll
                for (int r = 0; r < 4; ++r) {
                    const int b = zMt*16 + lq*4 + r;
                    rsxS[pcn][b][lm] = ra[r];
                    if (rks == idxv) ((unsigned short*)pubB[b])[lm & 7] = f2bf(ra[r]);
                }
            }
        }

        // ---- POLL: per-wave tag check (equality) then bulk gather+scatter ----
        {
            const unsigned* RecT = (const unsigned*)(ws + OFF_REC) + (size_t)(pc*2 + d)*32768;
            const int lbase = wave*512 + lane;
            for (;;) {
                unsigned bad = 0;
#pragma unroll
                for (int i = 0; i < 8; ++i)
                    bad |= (ald32(RecT + (size_t)(lbase + i*64)*16) != want) ? 1u : 0u;
                if (__ballot(bad != 0u) == 0ULL) break;
                __builtin_amdgcn_s_sleep(1);
            }
            asm volatile("" ::: "memory");
            const u64* RecU = (const u64*)(ws + OFF_REC) + (size_t)(pc*2 + d)*16384;
            const int role = lane & 7;   // 1:h 2:chi 3:clo 5:rsx (0,4,6,7: pad/tag)
            if (role == 1 || role == 2 || role == 3 || role == 5) {
#pragma unroll
                for (int i = 0; i < 32; ++i) {
                    const int c = wave*2048 + i*64 + lane;
                    u64x2 pk;
                    pk.x = ald64(RecU + ((size_t)c << 1));
                    pk.y = ald64(RecU + ((size_t)c << 1) + 1);
                    const int line = c >> 2;
                    const int g2 = (line >> 6) & 31, b = (line >> 1) & 31;
                    unsigned short* dst =
                        (role == 1) ? (sA + (size_t)((((b>>4)*16 + (g2>>2))*4 + (g2&3))*16 + (b&15))*8)
                      : (role == 2) ? &chiL[b][g2*8]
                      : (role == 3) ? &cloL[b][g2*8]
                      :               &rL[b][g2*8];
                    *(u64x2*)dst = pk;
                }
            }
        }
        __syncthreads();                                   // S4

        // ---- P4: wave3 publishes rsx' lines ; replicated r[idx] GEMM ----
        if (wave == 3 && more) {
            if (lane < 32) {
                u64x2 v = *(const u64x2*)&pubB[lane][0];
                gst16((u64*)(ws + OFF_REC) + ((size_t)(pcn*2 + d)*16384 + ((size_t)g*64 + lane*2 + 1)*8) + 2, v);
            }
            asm volatile("s_waitcnt vmcnt(0)" ::: "memory");
            if (lane < 32)
                ast32u((unsigned*)(ws + OFF_REC) + (size_t)(pcn*2 + d)*32768 + ((size_t)g*64 + lane*2 + 1)*16, want + 1);
        }
#pragma unroll
        for (int Mt = 0; Mt < 2; ++Mt) {
            bf16x8 hfB[8];
#pragma unroll
            for (int kt = 0; kt < 8; ++kt)
                hfB[kt] = *(const bf16x8*)(sA + (size_t)(Mt*8192 + kt*512 + lq*128 + lm*8));
            if (wave < 2 && Mt == wave) {          // rsh (own 16 cols) for P5
                f32x4 ra = {0.f, 0.f, 0.f, 0.f};
#pragma unroll
                for (int kt = 0; kt < 8; ++kt)
                    ra = __builtin_amdgcn_mfma_f32_16x16x32_bf16(hfB[kt], rwf[kt], ra, 0, 0, 0);
#pragma unroll
                for (int r = 0; r < 4; ++r) rshS[wave*16 + lq*4 + r][lm] = ra[r];
            }
            const int bb = Mt*16 + lm;
            const float mv = mL[bb];
#pragma unroll
            for (int n = 0; n < 4; ++n) {
                f32x4 a = {0.f, 0.f, 0.f, 0.f};
#pragma unroll
                for (int kt = 0; kt < 8; ++kt)
                    a = __builtin_amdgcn_mfma_f32_16x16x32_bf16(wbig[n][kt], hfB[kt], a, 0, 0, 0);
                const int j0 = wave*64 + n*16 + lq*4;
                const u64 hi64 = *(const u64*)&chiL[bb][j0];
                const u64 lo64 = *(const u64*)&cloL[bb][j0];
                const u64 rv64 = *(const u64*)&rL[bb][j0];
                u64 pk = 0ULL;
                float4 o4;
#pragma unroll
                for (int r = 0; r < 4; ++r) {
                    float cv = bfhi((unsigned short)(hi64 >> (r*16))) + bfhi((unsigned short)(lo64 >> (r*16)));
                    float rx = bfhi((unsigned short)(rv64 >> (r*16)));
                    float rr = sigm(a[r] + rx + brj[n*4 + r]);
                    float so = sreg[Mt][n][r];
                    float sn = rr*so + (1.f - rr)*cv;
                    float su = mv*sn + (1.f - mv)*so;
                    sreg[Mt][n][r] = su;
                    pk |= (u64)f2bf(su) << (r*16);
                    if (r == 0) o4.x = su; else if (r == 1) o4.y = su; else if (r == 2) o4.z = su; else o4.w = su;
                }
                const int ktp = 8 + (j0 >> 5);
                const int lqv = (j0 >> 3) & 3;
                const int half = (j0 >> 2) & 1;
                *(u64*)(sA + (size_t)((((Mt*16 + ktp)*4 + lqv)*16 + lm)*8 + half*4)) = pk;
                if ((j0 >> 3) == g)
                    *(float4*)(out + 33554432 + (((size_t)idxv*1024 + tx)*32 + bb)*512 + d*256 + j0) = o4;
            }
        }
        __syncthreads();                                   // S5

        // ---- P5: output-only share (1-idx) ----
        {
            const int k1 = 1 - idxv;
            float rv = rsxS[pc][eb][k1*8 + ej] + rshS[eb][k1*8 + ej] + (k1 ? brr1 : brr0);
            float rr = sigm(rv);
            float sn = rr*s1prev + (1.f - rr)*cu_;
            float su = m_*sn + (1.f - m_)*s1prev;
            s1prev = su;
            out[33554432 + (((size_t)k1*1024 + tx)*32 + eb)*512 + d*256 + gj] = su;
        }
    }
}

// ---------------------------------------------------------------------------
extern "C" void kernel_launch(void* const* d_in, const int* in_sizes, int n_in,
                              void* d_out, int out_size, void* d_ws, size_t ws_size,
                              hipStream_t stream) {
    const float* inputs = (const float*)d_in[0];
    const float* mask_  = (const float*)d_in[1];
    const float* Wx0  = (const float*)d_in[2];
    const float* Wh0  = (const float*)d_in[3];
    const float* Ws0  = (const float*)d_in[4];
    const float* b0   = (const float*)d_in[5];
    const float* Wrx0 = (const float*)d_in[6];
    const float* Wrh0 = (const float*)d_in[7];
    const float* br0  = (const float*)d_in[8];
    const float* Wx1  = (const float*)d_in[9];
    const float* Wh1  = (const float*)d_in[10];
    const float* Ws1  = (const float*)d_in[11];
    const float* b1   = (const float*)d_in[12];
    const float* Wrx1 = (const float*)d_in[13];
    const float* Wrh1 = (const float*)d_in[14];
    const float* br1  = (const float*)d_in[15];
    const int*   idxp = (const int*)d_in[16];
    unsigned char* ws = (unsigned char*)d_ws;

    hipLaunchKernelGGL(prepass, dim3(512), dim3(256), 0, stream,
                       Wx0, Wh0, Ws0, Wx1, Wh1, Ws1, Wrx0, Wrh0, Wrx1, Wrh1, ws);
    hipLaunchKernelGGL(bislstm, dim3(64), dim3(256), 0, stream,
                       inputs, mask_, b0, b1, br0, br1, idxp,
                       ws, (float*)d_out);
}